// Round 7
// baseline (511.430 us; speedup 1.0000x reference)
//
#include <hip/hip_runtime.h>
#include <hip/hip_bf16.h>

typedef __attribute__((ext_vector_type(8))) short short8;
typedef __attribute__((ext_vector_type(4))) float f32x4;

#define V_ 50000
#define E_ 300000
#define B_ 4
#define LAT_ 512
#define H_ 128
#define L_ 3
#define N_ (B_*V_)

#define SCAN_B 512
#define SCAN_G ((V_ + SCAN_B - 1) / SCAN_B)   // 98

__device__ inline void bsplit(float v, ushort& hi, ushort& lo) {
    __hip_bfloat16 hb = __float2bfloat16(v);
    float hf = __bfloat162float(hb);
    __hip_bfloat16 lb = __float2bfloat16(v - hf);
    hi = *(ushort*)&hb; lo = *(ushort*)&lb;
}

// ---------------------------------------------------------------------------
// Graph preprocessing (unchanged, verified)
// ---------------------------------------------------------------------------

__global__ void k_zero(int* __restrict__ deg, int* __restrict__ cursor) {
    int i = blockIdx.x * 256 + threadIdx.x;
    if (i < V_) { deg[i] = 0; cursor[i] = 0; }
}

__global__ void k_deg(const int* __restrict__ dst, int* __restrict__ deg) {
    int e = blockIdx.x * 256 + threadIdx.x;
    if (e < E_) atomicAdd(&deg[dst[e]], 1);
}

__global__ __launch_bounds__(SCAN_B) void k_scan1(const int* __restrict__ deg,
                                                  int* __restrict__ off,
                                                  float* __restrict__ dis,
                                                  int* __restrict__ part) {
    int t = threadIdx.x;
    int i = blockIdx.x * SCAN_B + t;
    int d = (i < V_) ? deg[i] : 0;
    __shared__ int sm[SCAN_B];
    sm[t] = d;
    __syncthreads();
    int val = d;
    for (int s = 1; s < SCAN_B; s <<= 1) {
        int o = (t >= s) ? sm[t - s] : 0;
        __syncthreads();
        val += o;
        sm[t] = val;
        __syncthreads();
    }
    if (i < V_) {
        off[i] = val - d;
        dis[i] = rsqrtf((float)(B_ * d + 1));
    }
    if (t == SCAN_B - 1) part[blockIdx.x] = val;
}

__global__ void k_scan2(int* __restrict__ part) {
    __shared__ int sm[128];
    int t = threadIdx.x;
    int v = (t < SCAN_G) ? part[t] : 0;
    sm[t] = v;
    __syncthreads();
    int val = v;
    for (int s = 1; s < 128; s <<= 1) {
        int o = (t >= s) ? sm[t - s] : 0;
        __syncthreads();
        val += o;
        sm[t] = val;
        __syncthreads();
    }
    if (t < SCAN_G) part[t] = val - v;
}

__global__ __launch_bounds__(SCAN_B) void k_scan3(int* __restrict__ off,
                                                  const int* __restrict__ part) {
    int i = blockIdx.x * SCAN_B + threadIdx.x;
    if (i < V_) off[i] += part[blockIdx.x];
    if (i == 0) off[V_] = E_;
}

__global__ void k_fill(const int* __restrict__ src, const int* __restrict__ dst,
                       const int* __restrict__ off, int* __restrict__ cursor,
                       int* __restrict__ csr) {
    int e = blockIdx.x * 256 + threadIdx.x;
    if (e < E_) {
        int c = dst[e];
        int p = atomicAdd(&cursor[c], 1);
        csr[off[c] + p] = src[e];
    }
}

// ---------------------------------------------------------------------------
// Weight split + small prep (unchanged layouts)
// ---------------------------------------------------------------------------

__global__ void k_wsplit(const float* __restrict__ W, ushort* __restrict__ Whi,
                         ushort* __restrict__ Wlo) {
    int i = blockIdx.x * 256 + threadIdx.x;
    float w = W[i];
    ushort hi, lo; bsplit(w, hi, lo);
    Whi[i] = hi; Wlo[i] = lo;
}

__global__ void k_prep(const float* __restrict__ Win, float* __restrict__ Wxyz) {
    int j = threadIdx.x;   // 128
    f32x4 v = {Win[(size_t)j*(LAT_+3)+0], Win[(size_t)j*(LAT_+3)+1],
               Win[(size_t)j*(LAT_+3)+2], 0.f};
    *(f32x4*)(Wxyz + j*4) = v;
}

__global__ void k_latproj(const float* __restrict__ Win, const float* __restrict__ bin,
                          const float* __restrict__ latent, float* __restrict__ latproj) {
    int t = blockIdx.x * 128 + threadIdx.x;
    if (t >= B_ * H_) return;
    int b = t >> 7, j = t & 127;
    const float* wr = Win + (size_t)j * (LAT_ + 3) + 3;
    const float* lp = latent + (size_t)b * LAT_;
    float s = bin[j];
    for (int k = 0; k < LAT_; k++) s = fmaf(wr[k], lp[k], s);
    latproj[t] = s;
}

// ---------------------------------------------------------------------------
// Transposed-register GEMM machinery (NO LDS, NO barriers).
// acc = W (A-operand, rows = out-feat) x x^T (B-operand, cols = nodes).
// C-layout (col=lane&15=node, row=kg*4+reg=feat) == next layer's B-frag
// layout lane-for-lane: bfrag[ks].u0 = pack(acc[2ks]), .u1 = pack(acc[2ks+1]).
// Each wave owns 32 nodes (2 ntiles), fully autonomous.
// ---------------------------------------------------------------------------

// compute one GEMM layer: acc[8][2] += W(layer) * B-frags
__device__ inline void gemm_layer(const ushort* __restrict__ Ah,
                                  const ushort* __restrict__ Al,
                                  int l15, int kg,
                                  const short8 bh[4][2], const short8 bl[4][2],
                                  f32x4 acc[8][2]) {
#pragma unroll
    for (int m = 0; m < 8; m++) {
        const ushort* ph = Ah + (m*16 + l15)*H_ + kg*4;
        const ushort* pl = Al + (m*16 + l15)*H_ + kg*4;
        short8 ah[4], al[4];
#pragma unroll
        for (int ks = 0; ks < 4; ks++) {
            union { short8 v; uint2 u[2]; } uh, ul;
            uh.u[0] = *(const uint2*)(ph + ks*32);
            uh.u[1] = *(const uint2*)(ph + ks*32 + 16);
            ul.u[0] = *(const uint2*)(pl + ks*32);
            ul.u[1] = *(const uint2*)(pl + ks*32 + 16);
            ah[ks] = uh.v; al[ks] = ul.v;
        }
#pragma unroll
        for (int ks = 0; ks < 4; ks++)
#pragma unroll
            for (int nt = 0; nt < 2; nt++) {
                acc[m][nt] = __builtin_amdgcn_mfma_f32_16x16x32_bf16(ah[ks], bh[ks][nt], acc[m][nt], 0,0,0);
                acc[m][nt] = __builtin_amdgcn_mfma_f32_16x16x32_bf16(ah[ks], bl[ks][nt], acc[m][nt], 0,0,0);
                acc[m][nt] = __builtin_amdgcn_mfma_f32_16x16x32_bf16(al[ks], bh[ks][nt], acc[m][nt], 0,0,0);
            }
    }
}

// bias+relu+split acc -> B-frags (in place over bh/bl)
__device__ inline void acc_to_bfrag(const f32x4 acc[8][2], const float* __restrict__ bias,
                                    int kg, short8 bh[4][2], short8 bl[4][2]) {
#pragma unroll
    for (int t = 0; t < 4; t++)
#pragma unroll
        for (int nt = 0; nt < 2; nt++) {
            union { short8 v; ushort s[8]; } uh, ul;
#pragma unroll
            for (int q = 0; q < 2; q++) {
                int m = 2*t + q;
                f32x4 b4 = *(const f32x4*)(bias + m*16 + kg*4);
#pragma unroll
                for (int j = 0; j < 4; j++) {
                    float s = fmaxf(acc[m][nt][j] + b4[j], 0.f);
                    bsplit(s, uh.s[q*4+j], ul.s[q*4+j]);
                }
            }
            bh[t][nt] = uh.v; bl[t][nt] = ul.v;
        }
}

// x0 B-frags for one ntile (b, v already resolved; dead lanes zeroed)
__device__ inline void x0_bfrag(const float* __restrict__ xyz, const float* __restrict__ lp,
                                const float* __restrict__ Wxyz, int v, bool ok, int kg, int nt,
                                short8 bh[4][2], short8 bl[4][2]) {
    float x0 = xyz[v*3+0], x1 = xyz[v*3+1], x2 = xyz[v*3+2];
#pragma unroll
    for (int ks = 0; ks < 4; ks++) {
        union { short8 v; ushort s[8]; } uh, ul;
#pragma unroll
        for (int q = 0; q < 2; q++)
#pragma unroll
            for (int j = 0; j < 4; j++) {
                int f = ks*32 + q*16 + kg*4 + j;
                f32x4 wx = *(const f32x4*)(Wxyz + f*4);
                float s = lp[f];
                s = fmaf(wx[0], x0, s);
                s = fmaf(wx[1], x1, s);
                s = fmaf(wx[2], x2, s);
                s = fmaxf(s, 0.f);
                if (!ok) s = 0.f;
                bsplit(s, uh.s[q*4+j], ul.s[q*4+j]);
            }
        bh[ks][nt] = uh.v; bl[ks][nt] = ul.v;
    }
}

// ---------------------------------------------------------------------------
// k_big2: batches 1..3 (no edges), fully fused x0 -> 3 layers -> head.
// 256 thr = 4 independent waves, 32 nodes each.  Zero LDS, zero barriers.
// ---------------------------------------------------------------------------

__global__ __launch_bounds__(256, 2) void k_big2(
        const float* __restrict__ xyz, const float* __restrict__ latproj,
        const float* __restrict__ Wxyz,
        const ushort* __restrict__ Whi, const ushort* __restrict__ Wlo,
        const float* __restrict__ convb,
        const float* __restrict__ Wout, const float* __restrict__ bout,
        float* __restrict__ out) {
    const int tid  = threadIdx.x;
    const int lane = tid & 63;
    const int l15  = lane & 15;
    const int kg   = lane >> 4;
    const int base = V_ + (blockIdx.x * 4 + (tid >> 6)) * 32;

    int node[2], vv[2]; bool ok[2];
    const float* lp[2];
#pragma unroll
    for (int nt = 0; nt < 2; nt++) {
        int n = base + nt*16 + l15;
        ok[nt] = (n < N_);
        int nn = ok[nt] ? n : 0;
        node[nt] = nn;
        int b = nn / V_;
        vv[nt] = nn - b * V_;
        lp[nt] = latproj + b * H_;
    }

    short8 bh[4][2], bl[4][2];
#pragma unroll
    for (int nt = 0; nt < 2; nt++)
        x0_bfrag(xyz, lp[nt], Wxyz, vv[nt], ok[nt], kg, nt, bh, bl);

    f32x4 acc[8][2];
    for (int l = 0; l < L_; l++) {
#pragma unroll
        for (int m = 0; m < 8; m++)
#pragma unroll
            for (int nt = 0; nt < 2; nt++) acc[m][nt] = (f32x4){0.f,0.f,0.f,0.f};
        gemm_layer(Whi + (size_t)l*H_*H_, Wlo + (size_t)l*H_*H_, l15, kg, bh, bl, acc);
        if (l < L_ - 1)
            acc_to_bfrag(acc, convb + l*H_, kg, bh, bl);
    }

    // ---- output head: relu(acc + b3) dot Wout, reduce over kg groups ----
    float p[2][3];
#pragma unroll
    for (int nt = 0; nt < 2; nt++) { p[nt][0] = 0.f; p[nt][1] = 0.f; p[nt][2] = 0.f; }
#pragma unroll
    for (int m = 0; m < 8; m++) {
        f32x4 b4 = *(const f32x4*)(convb + 2*H_ + m*16 + kg*4);
        f32x4 w0 = *(const f32x4*)(Wout + 0*H_ + m*16 + kg*4);
        f32x4 w1 = *(const f32x4*)(Wout + 1*H_ + m*16 + kg*4);
        f32x4 w2 = *(const f32x4*)(Wout + 2*H_ + m*16 + kg*4);
#pragma unroll
        for (int nt = 0; nt < 2; nt++)
#pragma unroll
            for (int j = 0; j < 4; j++) {
                float s = fmaxf(acc[m][nt][j] + b4[j], 0.f);
                p[nt][0] = fmaf(s, w0[j], p[nt][0]);
                p[nt][1] = fmaf(s, w1[j], p[nt][1]);
                p[nt][2] = fmaf(s, w2[j], p[nt][2]);
            }
    }
#pragma unroll
    for (int nt = 0; nt < 2; nt++)
#pragma unroll
        for (int o = 0; o < 3; o++) {
            p[nt][o] += __shfl_xor(p[nt][o], 16);
            p[nt][o] += __shfl_xor(p[nt][o], 32);
        }
    if (kg == 0) {
#pragma unroll
        for (int nt = 0; nt < 2; nt++)
            if (ok[nt]) {
                out[(size_t)node[nt]*3 + 0] = p[nt][0] + bout[0];
                out[(size_t)node[nt]*3 + 1] = p[nt][1] + bout[1];
                out[(size_t)node[nt]*3 + 2] = p[nt][2] + bout[2];
            }
    }
}

// ---------------------------------------------------------------------------
// k_lay0: batch-0 single GEMM h = x @ W^T (transposed-register scheme).
// MODE 0: x0 in-kernel.  MODE 1: B-frags gathered from xh/xl (node-major).
// Epilogue: coalesced f32x4 h stores (node-major).
// ---------------------------------------------------------------------------

template<int MODE>
__global__ __launch_bounds__(256, 2) void k_lay0(
        const ushort* __restrict__ xh, const ushort* __restrict__ xl,
        const float* __restrict__ xyz, const float* __restrict__ latproj,
        const float* __restrict__ Wxyz,
        const ushort* __restrict__ Whp, const ushort* __restrict__ Wlp,
        float* __restrict__ h) {
    const int tid  = threadIdx.x;
    const int lane = tid & 63;
    const int l15  = lane & 15;
    const int kg   = lane >> 4;
    const int base = (blockIdx.x * 4 + (tid >> 6)) * 32;

    int node[2]; bool ok[2];
#pragma unroll
    for (int nt = 0; nt < 2; nt++) {
        int n = base + nt*16 + l15;
        ok[nt] = (n < V_);
        node[nt] = ok[nt] ? n : 0;
    }

    short8 bh[4][2], bl[4][2];
    if (MODE == 0) {
#pragma unroll
        for (int nt = 0; nt < 2; nt++)
            x0_bfrag(xyz, latproj, Wxyz, node[nt], ok[nt], kg, nt, bh, bl);
    } else {
#pragma unroll
        for (int nt = 0; nt < 2; nt++) {
            const ushort* ph = xh + (size_t)node[nt]*H_ + kg*4;
            const ushort* pl = xl + (size_t)node[nt]*H_ + kg*4;
#pragma unroll
            for (int ks = 0; ks < 4; ks++) {
                union { short8 v; uint2 u[2]; } uh, ul;
                uh.u[0] = *(const uint2*)(ph + ks*32);
                uh.u[1] = *(const uint2*)(ph + ks*32 + 16);
                ul.u[0] = *(const uint2*)(pl + ks*32);
                ul.u[1] = *(const uint2*)(pl + ks*32 + 16);
                bh[ks][nt] = uh.v; bl[ks][nt] = ul.v;
            }
        }
    }

    f32x4 acc[8][2];
#pragma unroll
    for (int m = 0; m < 8; m++)
#pragma unroll
        for (int nt = 0; nt < 2; nt++) acc[m][nt] = (f32x4){0.f,0.f,0.f,0.f};
    gemm_layer(Whp, Wlp, l15, kg, bh, bl, acc);

    // coalesced h store: acc[m][nt] = feats m*16+kg*4+{0..3} of node[nt]
#pragma unroll
    for (int m = 0; m < 8; m++)
#pragma unroll
        for (int nt = 0; nt < 2; nt++)
            if (ok[nt])
                *(f32x4*)(h + (size_t)node[nt]*H_ + m*16 + kg*4) = acc[m][nt];
}

// ---------------------------------------------------------------------------
// Aggregation (batch-0).  One wave per node; lane-parallel CSR prefetch.
// (unchanged, verified)
// ---------------------------------------------------------------------------

template<bool FINAL>
__global__ __launch_bounds__(256) void k_agg0(const float* __restrict__ h,
                                              const float* __restrict__ dis,
                                              const int* __restrict__ off,
                                              const int* __restrict__ csr,
                                              const float* __restrict__ bias,
                                              ushort* __restrict__ xh_out,
                                              ushort* __restrict__ xl_out,
                                              const float* __restrict__ Wout,
                                              const float* __restrict__ bout,
                                              float* __restrict__ out) {
    int c = blockIdx.x * 4 + (threadIdx.x >> 6);
    int lane = threadIdx.x & 63;
    if (c >= V_) return;
    int beg = off[c], end = off[c + 1];
    int nu = end - beg;
    int   myu  = (lane < nu) ? csr[beg + lane] : 0;
    float mywu = (lane < nu) ? dis[myu] : 0.f;
    float a0 = 0.f, a1 = 0.f;
    int nn = nu < 64 ? nu : 64;
    for (int i = 0; i < nn; i++) {
        int u = __shfl(myu, i);
        float wu = __shfl(mywu, i);
        const float* hu = h + (size_t)u * 128;
        a0 = fmaf(wu, hu[lane],      a0);
        a1 = fmaf(wu, hu[lane + 64], a1);
    }
    for (int i = beg + 64; i < end; i++) {
        int u = csr[i];
        float wu = dis[u];
        const float* hu = h + (size_t)u * 128;
        a0 = fmaf(wu, hu[lane],      a0);
        a1 = fmaf(wu, hu[lane + 64], a1);
    }
    float dc = dis[c];
    const float* hr = h + (size_t)c * 128;
    float s0 = fmaxf(dc * (float)B_ * a0 + dc * dc * hr[lane]      + bias[lane],      0.f);
    float s1 = fmaxf(dc * (float)B_ * a1 + dc * dc * hr[lane + 64] + bias[lane + 64], 0.f);
    if (FINAL) {
        float p0 = s0 * Wout[0*H_ + lane] + s1 * Wout[0*H_ + 64 + lane];
        float p1 = s0 * Wout[1*H_ + lane] + s1 * Wout[1*H_ + 64 + lane];
        float p2 = s0 * Wout[2*H_ + lane] + s1 * Wout[2*H_ + 64 + lane];
#pragma unroll
        for (int d = 32; d; d >>= 1) {
            p0 += __shfl_down(p0, d);
            p1 += __shfl_down(p1, d);
            p2 += __shfl_down(p2, d);
        }
        if (lane == 0) {
            out[(size_t)c*3 + 0] = p0 + bout[0];
            out[(size_t)c*3 + 1] = p1 + bout[1];
            out[(size_t)c*3 + 2] = p2 + bout[2];
        }
    } else {
        ushort h0, l0, h1, l1;
        bsplit(s0, h0, l0);
        bsplit(s1, h1, l1);
        xh_out[(size_t)c*128 + lane]      = h0;
        xl_out[(size_t)c*128 + lane]      = l0;
        xh_out[(size_t)c*128 + lane + 64] = h1;
        xl_out[(size_t)c*128 + lane + 64] = l1;
    }
}

// ---------------------------------------------------------------------------

extern "C" void kernel_launch(void* const* d_in, const int* in_sizes, int n_in,
                              void* d_out, int out_size, void* d_ws, size_t ws_size,
                              hipStream_t stream) {
    const float* xyz    = (const float*)d_in[0];
    const float* latent = (const float*)d_in[1];
    const int*   ei     = (const int*)d_in[2];
    const float* Win    = (const float*)d_in[3];
    const float* bin    = (const float*)d_in[4];
    const float* convW  = (const float*)d_in[5];
    const float* convb  = (const float*)d_in[6];
    const float* Wout   = (const float*)d_in[7];
    const float* bout   = (const float*)d_in[8];
    float* out = (float*)d_out;

    char* w = (char*)d_ws;
    auto carve = [&](size_t bytes) {
        char* p = w;
        w += (bytes + 255) & ~(size_t)255;
        return p;
    };
    ushort* xh      = (ushort*)carve((size_t)V_ * H_ * 2);
    ushort* xl      = (ushort*)carve((size_t)V_ * H_ * 2);
    float*  h       = (float*)carve((size_t)V_ * H_ * 4);
    ushort* Whi     = (ushort*)carve((size_t)L_ * H_ * H_ * 2);
    ushort* Wlo     = (ushort*)carve((size_t)L_ * H_ * H_ * 2);
    float*  dis     = (float*)carve((size_t)V_ * 4);
    float*  latproj = (float*)carve((size_t)B_ * H_ * 4);
    float*  Wxyz    = (float*)carve((size_t)H_ * 4 * 4);
    int*    deg     = (int*)carve((size_t)V_ * 4);
    int*    off     = (int*)carve((size_t)(V_ + 1) * 4);
    int*    cursor  = (int*)carve((size_t)V_ * 4);
    int*    csr     = (int*)carve((size_t)E_ * 4);
    int*    part    = (int*)carve((size_t)SCAN_G * 4);
    (void)ws_size; (void)in_sizes; (void)n_in; (void)out_size;

    const int* src = ei;
    const int* dst = ei + E_;

    k_zero<<<(V_ + 255) / 256, 256, 0, stream>>>(deg, cursor);
    k_deg<<<(E_ + 255) / 256, 256, 0, stream>>>(dst, deg);
    k_scan1<<<SCAN_G, SCAN_B, 0, stream>>>(deg, off, dis, part);
    k_scan2<<<1, 128, 0, stream>>>(part);
    k_scan3<<<SCAN_G, SCAN_B, 0, stream>>>(off, part);
    k_fill<<<(E_ + 255) / 256, 256, 0, stream>>>(src, dst, off, cursor, csr);

    k_wsplit<<<(L_ * H_ * H_) / 256, 256, 0, stream>>>(convW, Whi, Wlo);
    k_prep<<<1, 128, 0, stream>>>(Win, Wxyz);
    k_latproj<<<4, 128, 0, stream>>>(Win, bin, latent, latproj);

    // batches 1..3: fully fused, wave-autonomous (150000 rows / 32 per wave)
    const int GB = ((N_ - V_) + 127) / 128;      // 4 waves * 32 rows per block
    k_big2<<<GB, 256, 0, stream>>>(xyz, latproj, Wxyz, Whi, Wlo,
                                   convb, Wout, bout, out);

    // batch 0 chain
    const int G0 = (V_ + 127) / 128;
    k_lay0<0><<<G0, 256, 0, stream>>>(nullptr, nullptr, xyz, latproj, Wxyz,
                                      Whi, Wlo, h);
    k_agg0<false><<<(V_ + 3) / 4, 256, 0, stream>>>(h, dis, off, csr, convb,
                                                    xh, xl, nullptr, nullptr, nullptr);
    k_lay0<1><<<G0, 256, 0, stream>>>(xh, xl, nullptr, nullptr, nullptr,
                                      Whi + (size_t)1*H_*H_, Wlo + (size_t)1*H_*H_, h);
    k_agg0<false><<<(V_ + 3) / 4, 256, 0, stream>>>(h, dis, off, csr, convb + 1*H_,
                                                    xh, xl, nullptr, nullptr, nullptr);
    k_lay0<1><<<G0, 256, 0, stream>>>(xh, xl, nullptr, nullptr, nullptr,
                                      Whi + (size_t)2*H_*H_, Wlo + (size_t)2*H_*H_, h);
    k_agg0<true><<<(V_ + 3) / 4, 256, 0, stream>>>(h, dis, off, csr, convb + 2*H_,
                                                   nullptr, nullptr, Wout, bout, out);
}

// Round 8
// 428.964 us; speedup vs baseline: 1.1922x; 1.1922x over previous
//
#include <hip/hip_runtime.h>
#include <hip/hip_bf16.h>

typedef __attribute__((ext_vector_type(8))) short short8;
typedef __attribute__((ext_vector_type(4))) float f32x4;

#define V_ 50000
#define E_ 300000
#define B_ 4
#define LAT_ 512
#define H_ 128
#define L_ 3
#define N_ (B_*V_)
#define NT_ (N_/64)          // 3125 tiles of 64 rows, exact

#define SCAN_B 512
#define SCAN_G ((V_ + SCAN_B - 1) / SCAN_B)   // 98

__device__ inline void bsplit(float v, ushort& hi, ushort& lo) {
    __hip_bfloat16 hb = __float2bfloat16(v);
    float hf = __bfloat162float(hb);
    __hip_bfloat16 lb = __float2bfloat16(v - hf);
    hi = *(ushort*)&hb; lo = *(ushort*)&lb;
}
__device__ inline float bjoin(ushort h, ushort l) {
    __hip_bfloat16 hb = *(__hip_bfloat16*)&h;
    __hip_bfloat16 lb = *(__hip_bfloat16*)&l;
    return __bfloat162float(hb) + __bfloat162float(lb);
}

__device__ inline void gload_lds16(const void* g, void* s) {
    __builtin_amdgcn_global_load_lds(
        (const __attribute__((address_space(1))) unsigned int*)g,
        (__attribute__((address_space(3))) unsigned int*)s, 16, 0, 0);
}

// ---------------------------------------------------------------------------
// Graph preprocessing (unchanged, verified)
// ---------------------------------------------------------------------------

__global__ void k_zero(int* __restrict__ deg, int* __restrict__ cursor) {
    int i = blockIdx.x * 256 + threadIdx.x;
    if (i < V_) { deg[i] = 0; cursor[i] = 0; }
}

__global__ void k_deg(const int* __restrict__ dst, int* __restrict__ deg) {
    int e = blockIdx.x * 256 + threadIdx.x;
    if (e < E_) atomicAdd(&deg[dst[e]], 1);
}

__global__ __launch_bounds__(SCAN_B) void k_scan1(const int* __restrict__ deg,
                                                  int* __restrict__ off,
                                                  float* __restrict__ dis,
                                                  int* __restrict__ part) {
    int t = threadIdx.x;
    int i = blockIdx.x * SCAN_B + t;
    int d = (i < V_) ? deg[i] : 0;
    __shared__ int sm[SCAN_B];
    sm[t] = d;
    __syncthreads();
    int val = d;
    for (int s = 1; s < SCAN_B; s <<= 1) {
        int o = (t >= s) ? sm[t - s] : 0;
        __syncthreads();
        val += o;
        sm[t] = val;
        __syncthreads();
    }
    if (i < V_) {
        off[i] = val - d;
        dis[i] = rsqrtf((float)(B_ * d + 1));
    }
    if (t == SCAN_B - 1) part[blockIdx.x] = val;
}

__global__ void k_scan2(int* __restrict__ part) {
    __shared__ int sm[128];
    int t = threadIdx.x;
    int v = (t < SCAN_G) ? part[t] : 0;
    sm[t] = v;
    __syncthreads();
    int val = v;
    for (int s = 1; s < 128; s <<= 1) {
        int o = (t >= s) ? sm[t - s] : 0;
        __syncthreads();
        val += o;
        sm[t] = val;
        __syncthreads();
    }
    if (t < SCAN_G) part[t] = val - v;
}

__global__ __launch_bounds__(SCAN_B) void k_scan3(int* __restrict__ off,
                                                  const int* __restrict__ part) {
    int i = blockIdx.x * SCAN_B + threadIdx.x;
    if (i < V_) off[i] += part[blockIdx.x];
    if (i == 0) off[V_] = E_;
}

__global__ void k_fill(const int* __restrict__ src, const int* __restrict__ dst,
                       const int* __restrict__ off, int* __restrict__ cursor,
                       int* __restrict__ csr) {
    int e = blockIdx.x * 256 + threadIdx.x;
    if (e < E_) {
        int c = dst[e];
        int p = atomicAdd(&cursor[c], 1);
        csr[off[c] + p] = src[e];
    }
}

// ---------------------------------------------------------------------------
// Weight split + small prep
// ---------------------------------------------------------------------------

__global__ void k_wsplit(const float* __restrict__ W, ushort* __restrict__ Whi,
                         ushort* __restrict__ Wlo) {
    int i = blockIdx.x * 256 + threadIdx.x;
    float w = W[i];
    ushort hi, lo; bsplit(w, hi, lo);
    Whi[i] = hi; Wlo[i] = lo;
}

__global__ void k_prep(const float* __restrict__ Win, float* __restrict__ Wxyz) {
    int j = threadIdx.x;   // 128
    f32x4 v = {Win[(size_t)j*(LAT_+3)+0], Win[(size_t)j*(LAT_+3)+1],
               Win[(size_t)j*(LAT_+3)+2], 0.f};
    *(f32x4*)(Wxyz + j*4) = v;
}

__global__ void k_latproj(const float* __restrict__ Win, const float* __restrict__ bin,
                          const float* __restrict__ latent, float* __restrict__ latproj) {
    int t = blockIdx.x * 128 + threadIdx.x;
    if (t >= B_ * H_) return;
    int b = t >> 7, j = t & 127;
    const float* wr = Win + (size_t)j * (LAT_ + 3) + 3;
    const float* lp = latent + (size_t)b * LAT_;
    float s = bin[j];
    for (int k = 0; k < LAT_; k++) s = fmaf(wr[k], lp[k], s);
    latproj[t] = s;
}

// ---------------------------------------------------------------------------
// k_x0: materialize x0 split planes for ALL N rows.
// thread = (node, 8-feature group); two 16B stores.
// ---------------------------------------------------------------------------

__global__ __launch_bounds__(256) void k_x0(const float* __restrict__ xyz,
                                            const float* __restrict__ latproj,
                                            const float* __restrict__ Wxyz,
                                            ushort* __restrict__ xh,
                                            ushort* __restrict__ xl) {
    int idx = blockIdx.x * 256 + threadIdx.x;     // over N_*16
    int node = idx >> 4;
    int c0 = (idx & 15) * 8;
    int b = node / V_, v = node - b * V_;
    float x0 = xyz[v*3+0], x1 = xyz[v*3+1], x2 = xyz[v*3+2];
    ushort hs[8], ls[8];
#pragma unroll
    for (int i = 0; i < 8; i++) {
        int f = c0 + i;
        f32x4 wx = *(const f32x4*)(Wxyz + f*4);
        float s = latproj[b*H_ + f];
        s = fmaf(wx[0], x0, s);
        s = fmaf(wx[1], x1, s);
        s = fmaf(wx[2], x2, s);
        s = fmaxf(s, 0.f);
        bsplit(s, hs[i], ls[i]);
    }
    *(uint4*)(xh + (size_t)node*H_ + c0) = *(uint4*)hs;
    *(uint4*)(xl + (size_t)node*H_ + c0) = *(uint4*)ls;
}

// ---------------------------------------------------------------------------
// k_layer: whole-layer GEMM over all N rows, persistent blocks.
// 512 thr = 8 waves = 2 row-groups x 4 col-pairs; tile 64 rows x 128 cols.
// Wave: 32 rows x 32 cols; W slab (hi+lo, 2x16 cols) held in registers for
// the whole kernel.  X tiles double-buffered in LDS via global_load_lds with
// PRE-SWIZZLED SOURCE chunks (LDS dest linear; involution chunk^=(row&7));
// b64 A-frag reads then hit 4 accesses/bank = conflict-free floor.
// Epilogue: rows < V -> f32 h; rows >= V -> relu(+bias), split, IN-PLACE x'.
// In-place is safe: each row is staged and written only by its own tile.
// ---------------------------------------------------------------------------

__global__ __launch_bounds__(512, 2) void k_layer(
        const ushort* __restrict__ xh, const ushort* __restrict__ xl,
        const ushort* __restrict__ Wh, const ushort* __restrict__ Wl,
        const float* __restrict__ bias,
        float* __restrict__ h,
        ushort* __restrict__ xho, ushort* __restrict__ xlo) {
    __shared__ __align__(16) char smem[65536];
    const int tid  = threadIdx.x;
    const int w    = tid >> 6;
    const int lane = tid & 63;
    const int l15  = lane & 15;
    const int kg   = lane >> 4;
    const int n0   = (w & 3) * 32;        // col base (2 slabs of 16)
    const int mrow = (w >> 2) * 32;       // row base within tile

    // ---- persistent W fragments (64 VGPR) ----
    short8 wh[2][4], wl[2][4];
#pragma unroll
    for (int nt = 0; nt < 2; nt++)
#pragma unroll
        for (int ks = 0; ks < 4; ks++) {
            const ushort* bh = Wh + (size_t)(n0 + nt*16 + l15)*H_ + ks*32 + kg*4;
            const ushort* bl = Wl + (size_t)(n0 + nt*16 + l15)*H_ + ks*32 + kg*4;
            union { short8 v; uint2 u[2]; } uh, ul;
            uh.u[0] = *(const uint2*)bh;  uh.u[1] = *(const uint2*)(bh + 16);
            ul.u[0] = *(const uint2*)bl;  ul.u[1] = *(const uint2*)(bl + 16);
            wh[nt][ks] = uh.v; wl[nt][ks] = ul.v;
        }

    const float bv[2] = { bias[n0 + l15], bias[n0 + 16 + l15] };

    // ---- staging: wave w covers tile rows [w*8, w*8+8), both planes ----
    const int srow = w * 8;
    const int rgl  = lane >> 4;           // 0..3
    const int cch  = lane & 15;           // dest 16B chunk
    auto stage = [&](int tile, int bufoff) {
#pragma unroll
        for (int i = 0; i < 4; i++) {
            int p  = i >> 1, rg = i & 1;
            int row = srow + rg*4 + rgl;
            int node = tile*64 + row;
            // source chunk pre-swizzled: LDS[r][c] = G[r][c ^ (r&7)]
            const ushort* src = (p ? xl : xh) + (size_t)node*H_ + ((cch ^ (row & 7)) << 3);
            char* dst = smem + bufoff + p*16384 + (srow + rg*4)*256;  // uniform base
            gload_lds16(src, dst);
        }
    };

    int tile = blockIdx.x;
    stage(tile, 0);
    __syncthreads();
    int buf = 0;

    for (; tile < NT_; tile += gridDim.x) {
        int nxt = tile + gridDim.x;
        if (nxt < NT_) stage(nxt, (buf ^ 1) * 32768);

        const char* sb = smem + buf * 32768;
        f32x4 acc[2][2];
        acc[0][0] = acc[0][1] = acc[1][0] = acc[1][1] = (f32x4){0.f,0.f,0.f,0.f};
        const int r7 = l15 & 7;
#pragma unroll
        for (int ks = 0; ks < 4; ks++) {
            short8 ah[2], al[2];
            const int cl = (((ks*4 + (kg>>1)) ^ r7) << 4) + (kg & 1) * 8;
            const int ch = (((ks*4 + (kg>>1) + 2) ^ r7) << 4) + (kg & 1) * 8;
#pragma unroll
            for (int mt = 0; mt < 2; mt++) {
                const char* rb = sb + (mrow + mt*16 + l15) * 256;
                union { short8 v; uint2 u[2]; } uh, ul;
                uh.u[0] = *(const uint2*)(rb + cl);
                uh.u[1] = *(const uint2*)(rb + ch);
                ul.u[0] = *(const uint2*)(rb + 16384 + cl);
                ul.u[1] = *(const uint2*)(rb + 16384 + ch);
                ah[mt] = uh.v; al[mt] = ul.v;
            }
#pragma unroll
            for (int mt = 0; mt < 2; mt++)
#pragma unroll
                for (int nt = 0; nt < 2; nt++) {
                    acc[mt][nt] = __builtin_amdgcn_mfma_f32_16x16x32_bf16(ah[mt], wh[nt][ks], acc[mt][nt], 0,0,0);
                    acc[mt][nt] = __builtin_amdgcn_mfma_f32_16x16x32_bf16(al[mt], wh[nt][ks], acc[mt][nt], 0,0,0);
                    acc[mt][nt] = __builtin_amdgcn_mfma_f32_16x16x32_bf16(ah[mt], wl[nt][ks], acc[mt][nt], 0,0,0);
                }
        }

        // ---- epilogue ----
        const int tbase = tile * 64 + mrow;
#pragma unroll
        for (int mt = 0; mt < 2; mt++)
#pragma unroll
            for (int nt = 0; nt < 2; nt++) {
                const int col = n0 + nt*16 + l15;
#pragma unroll
                for (int j = 0; j < 4; j++) {
                    int node = tbase + mt*16 + kg*4 + j;
                    float v = acc[mt][nt][j];
                    if (node < V_) {
                        h[(size_t)node*H_ + col] = v;
                    } else {
                        float s = fmaxf(v + bv[nt], 0.f);
                        ushort hi, lo; bsplit(s, hi, lo);
                        xho[(size_t)node*H_ + col] = hi;
                        xlo[(size_t)node*H_ + col] = lo;
                    }
                }
            }
        __syncthreads();
        buf ^= 1;
    }
}

// ---------------------------------------------------------------------------
// Aggregation (batch-0).  One wave per node; lane-parallel CSR prefetch.
// ---------------------------------------------------------------------------

template<bool FINAL>
__global__ __launch_bounds__(256) void k_agg0(const float* __restrict__ h,
                                              const float* __restrict__ dis,
                                              const int* __restrict__ off,
                                              const int* __restrict__ csr,
                                              const float* __restrict__ bias,
                                              ushort* __restrict__ xh_out,
                                              ushort* __restrict__ xl_out,
                                              const float* __restrict__ Wout,
                                              const float* __restrict__ bout,
                                              float* __restrict__ out) {
    int c = blockIdx.x * 4 + (threadIdx.x >> 6);
    int lane = threadIdx.x & 63;
    if (c >= V_) return;
    int beg = off[c], end = off[c + 1];
    int nu = end - beg;
    int   myu  = (lane < nu) ? csr[beg + lane] : 0;
    float mywu = (lane < nu) ? dis[myu] : 0.f;
    float a0 = 0.f, a1 = 0.f;
    int nn = nu < 64 ? nu : 64;
    for (int i = 0; i < nn; i++) {
        int u = __shfl(myu, i);
        float wu = __shfl(mywu, i);
        const float* hu = h + (size_t)u * 128;
        a0 = fmaf(wu, hu[lane],      a0);
        a1 = fmaf(wu, hu[lane + 64], a1);
    }
    for (int i = beg + 64; i < end; i++) {
        int u = csr[i];
        float wu = dis[u];
        const float* hu = h + (size_t)u * 128;
        a0 = fmaf(wu, hu[lane],      a0);
        a1 = fmaf(wu, hu[lane + 64], a1);
    }
    float dc = dis[c];
    const float* hr = h + (size_t)c * 128;
    float s0 = fmaxf(dc * (float)B_ * a0 + dc * dc * hr[lane]      + bias[lane],      0.f);
    float s1 = fmaxf(dc * (float)B_ * a1 + dc * dc * hr[lane + 64] + bias[lane + 64], 0.f);
    if (FINAL) {
        float p0 = s0 * Wout[0*H_ + lane] + s1 * Wout[0*H_ + 64 + lane];
        float p1 = s0 * Wout[1*H_ + lane] + s1 * Wout[1*H_ + 64 + lane];
        float p2 = s0 * Wout[2*H_ + lane] + s1 * Wout[2*H_ + 64 + lane];
#pragma unroll
        for (int d = 32; d; d >>= 1) {
            p0 += __shfl_down(p0, d);
            p1 += __shfl_down(p1, d);
            p2 += __shfl_down(p2, d);
        }
        if (lane == 0) {
            out[(size_t)c*3 + 0] = p0 + bout[0];
            out[(size_t)c*3 + 1] = p1 + bout[1];
            out[(size_t)c*3 + 2] = p2 + bout[2];
        }
    } else {
        ushort h0, l0, h1, l1;
        bsplit(s0, h0, l0);
        bsplit(s1, h1, l1);
        xh_out[(size_t)c*128 + lane]      = h0;
        xl_out[(size_t)c*128 + lane]      = l0;
        xh_out[(size_t)c*128 + lane + 64] = h1;
        xl_out[(size_t)c*128 + lane + 64] = l1;
    }
}

// ---------------------------------------------------------------------------
// Output head for batches 1..3 (rows >= V).  One wave per node.
// ---------------------------------------------------------------------------

__global__ __launch_bounds__(256) void k_out(const ushort* __restrict__ xh,
                                             const ushort* __restrict__ xl,
                                             const float* __restrict__ Wout,
                                             const float* __restrict__ bout,
                                             float* __restrict__ out) {
    int n = V_ + (int)(((size_t)blockIdx.x * 256 + threadIdx.x) >> 6);
    int lane = threadIdx.x & 63;
    if (n >= N_) return;
    const ushort* ph = xh + (size_t)n * 128;
    const ushort* pl = xl + (size_t)n * 128;
    ushort u0h = ph[lane], u0l = pl[lane], u1h = ph[lane + 64], u1l = pl[lane + 64];
    float x0 = bjoin(u0h, u0l);
    float x1 = bjoin(u1h, u1l);
#pragma unroll
    for (int o = 0; o < 3; o++) {
        float a = x0 * Wout[o * 128 + lane] + x1 * Wout[o * 128 + 64 + lane];
#pragma unroll
        for (int d = 32; d; d >>= 1) a += __shfl_down(a, d);
        if (lane == 0) out[(size_t)n * 3 + o] = a + bout[o];
    }
}

// ---------------------------------------------------------------------------

extern "C" void kernel_launch(void* const* d_in, const int* in_sizes, int n_in,
                              void* d_out, int out_size, void* d_ws, size_t ws_size,
                              hipStream_t stream) {
    const float* xyz    = (const float*)d_in[0];
    const float* latent = (const float*)d_in[1];
    const int*   ei     = (const int*)d_in[2];
    const float* Win    = (const float*)d_in[3];
    const float* bin    = (const float*)d_in[4];
    const float* convW  = (const float*)d_in[5];
    const float* convb  = (const float*)d_in[6];
    const float* Wout   = (const float*)d_in[7];
    const float* bout   = (const float*)d_in[8];
    float* out = (float*)d_out;

    char* w = (char*)d_ws;
    auto carve = [&](size_t bytes) {
        char* p = w;
        w += (bytes + 255) & ~(size_t)255;
        return p;
    };
    ushort* xh      = (ushort*)carve((size_t)N_ * H_ * 2);
    ushort* xl      = (ushort*)carve((size_t)N_ * H_ * 2);
    float*  h       = (float*)carve((size_t)V_ * H_ * 4);
    ushort* Whi     = (ushort*)carve((size_t)L_ * H_ * H_ * 2);
    ushort* Wlo     = (ushort*)carve((size_t)L_ * H_ * H_ * 2);
    float*  dis     = (float*)carve((size_t)V_ * 4);
    float*  latproj = (float*)carve((size_t)B_ * H_ * 4);
    float*  Wxyz    = (float*)carve((size_t)H_ * 4 * 4);
    int*    deg     = (int*)carve((size_t)V_ * 4);
    int*    off     = (int*)carve((size_t)(V_ + 1) * 4);
    int*    cursor  = (int*)carve((size_t)V_ * 4);
    int*    csr     = (int*)carve((size_t)E_ * 4);
    int*    part    = (int*)carve((size_t)SCAN_G * 4);
    (void)ws_size; (void)in_sizes; (void)n_in; (void)out_size;

    const int* src = ei;
    const int* dst = ei + E_;

    k_zero<<<(V_ + 255) / 256, 256, 0, stream>>>(deg, cursor);
    k_deg<<<(E_ + 255) / 256, 256, 0, stream>>>(dst, deg);
    k_scan1<<<SCAN_G, SCAN_B, 0, stream>>>(deg, off, dis, part);
    k_scan2<<<1, 128, 0, stream>>>(part);
    k_scan3<<<SCAN_G, SCAN_B, 0, stream>>>(off, part);
    k_fill<<<(E_ + 255) / 256, 256, 0, stream>>>(src, dst, off, cursor, csr);

    k_wsplit<<<(L_ * H_ * H_) / 256, 256, 0, stream>>>(convW, Whi, Wlo);
    k_prep<<<1, 128, 0, stream>>>(Win, Wxyz);
    k_latproj<<<4, 128, 0, stream>>>(Win, bin, latent, latproj);

    // x0 split planes for ALL rows
    k_x0<<<(N_ * 16) / 256, 256, 0, stream>>>(xyz, latproj, Wxyz, xh, xl);

    for (int l = 0; l < L_; l++) {
        k_layer<<<512, 512, 0, stream>>>(xh, xl,
                                         Whi + (size_t)l * H_ * H_,
                                         Wlo + (size_t)l * H_ * H_,
                                         convb + (size_t)l * H_,
                                         h, xh, xl);
        if (l < L_ - 1)
            k_agg0<false><<<(V_ + 3) / 4, 256, 0, stream>>>(h, dis, off, csr,
                                                            convb + (size_t)l * H_,
                                                            xh, xl, nullptr, nullptr, nullptr);
        else
            k_agg0<true><<<(V_ + 3) / 4, 256, 0, stream>>>(h, dis, off, csr,
                                                           convb + (size_t)l * H_,
                                                           nullptr, nullptr, Wout, bout, out);
    }

    // batches 1..3 output head
    k_out<<<(N_ - V_) / 4, 256, 0, stream>>>(xh, xl, Wout, bout, out);
}